// Round 15
// baseline (546.190 us; speedup 1.0000x reference)
//
#include <hip/hip_runtime.h>
#include <stdint.h>

// Problem constants (fixed instance)
#define B_    32
#define S_    4096
#define E_    256
#define P_    256
#define M_    16
#define G_    (B_*P_)      // 8192 groups
#define NSLOT (G_*M_)      // 131072 slots (== tokens)
#define GPW   8            // groups per workgroup
#define ROWS  128          // 8 groups * 16 slots
#define NWG   (G_/GPW)     // 1024 workgroups

typedef float fv4 __attribute__((ext_vector_type(4)));
typedef int   iv4 __attribute__((ext_vector_type(4)));
typedef int   iv2 __attribute__((ext_vector_type(2)));
typedef __bf16 bv8 __attribute__((ext_vector_type(8)));
typedef short  sv4 __attribute__((ext_vector_type(4)));

__device__ __forceinline__ uint32_t bf16rne(float f) {
  uint32_t u = __builtin_bit_cast(uint32_t, f);
  u += 0x7fffu + ((u >> 16) & 1u);
  return u >> 16;
}
__device__ __forceinline__ uint32_t pk2(uint32_t lo, uint32_t hi) {
  return (lo & 0xffffu) | (hi << 16);
}
// Builtins (NOT inline asm): hazard recognizer must see MFMAs (round-1 NaN).
__device__ __forceinline__ void mfma32(fv4& d, iv4 a, iv4 b) {
  d = __builtin_amdgcn_mfma_f32_16x16x32_bf16(
        __builtin_bit_cast(bv8, a), __builtin_bit_cast(bv8, b), d, 0, 0, 0);
}
__device__ __forceinline__ void mfma16(fv4& d, iv2 a, iv2 b) {
  d = __builtin_amdgcn_mfma_f32_16x16x16bf16_1k(
        __builtin_bit_cast(sv4, a), __builtin_bit_cast(sv4, b), d, 0, 0, 0);
}

// XOR swizzle for 512B rows: flips byte bits 4-6 by row&7 (involution).
#define SWZ(off, row) ((off) ^ (((row) & 7) << 4))
// 64B-row buffers (Q/K/V/C [128][32]bf16) stored [pair][128B], pair-swizzled.
#define LQKV(row, cb) ( ((row) >> 1) * 128 + \
    (((((row) & 1) << 6) + (cb)) ^ ((((row) >> 1) & 7) << 4)) )

// ---------------- prep kernels ----------------
__global__ void k_init(int* cnt, int* s2t) {
  int i = blockIdx.x * 256 + threadIdx.x;
  if (i < G_) cnt[i] = 0;
  if (i < NSLOT) s2t[i] = -1;
}

__global__ void k_trans(const float* __restrict__ Wq, const float* __restrict__ Wk,
                        const float* __restrict__ Wv, const float* __restrict__ W0,
                        uint16_t* __restrict__ WT) {
  // WT: 4 concatenated [256][256] bf16, WT[w][n][k] = bf16(W[w][k][n])
  int o = blockIdx.x * 256 + threadIdx.x;     // 0..65535
  int wsel = blockIdx.y;
  const float* W = (wsel == 0) ? Wq : (wsel == 1) ? Wk : (wsel == 2) ? Wv : W0;
  int n = o >> 8, k = o & 255;
  WT[(size_t)wsel * 65536 + o] = (uint16_t)bf16rne(W[k * 256 + n]);
}

__global__ void k_rank(const int* __restrict__ pos, int* cnt, int* s2t) {
  int i = blockIdx.x * 256 + threadIdx.x;
  if (i >= B_ * S_) return;
  int p = pos[i];
  if (p < 0 || p >= P_) return;          // invalid -> dropped (stays -1)
  int b = i >> 12;                       // i / S_
  int g = (b << 8) + p;
  int r = atomicAdd(&cnt[g], 1);         // arbitrary slot order: attention is
  if (r < M_) s2t[g * M_ + r] = i;       // permutation-equivariant, so OK
}

// ---------------- fused main kernel ----------------
// 1 WG = 8 groups = 128 rows, 1024 threads = 16 waves (arch VGPR pinned to
// 64 for 1024-thr WGs -> 4 waves/SIMD; measured r2..r14).
// r15 change vs r8: NO LDS weight staging. W fragments are read DIRECTLY
// from global as MFMA B-operands: per-matrix chunk tile = 16 KB -> L1-
// resident after first touch (L1 32KB, ~2x LDS BW). This deletes both
// stage buffers, all global_load_lds, the hand-vmcnt ledger (fragile vs
// spills: r11/r12/r14), and 5 of 8 barriers/chunk. LDS holds only X
// (gather overlay) and the Q/K/V/C transpose buffers. Compiler inserts
// all waitcnts -> correctness independent of spills.
__global__ __launch_bounds__(1024) void k_main(
    const float* __restrict__ emb, const int* __restrict__ s2t,
    const uint16_t* __restrict__ WT, float* __restrict__ out) {
  extern __shared__ char smem[];
  // gather overlay uses [0, 64K); after xf extraction the low 32K is reused:
  char* Qb = smem;              // 8 KiB [128][32] bf16, pair-swizzled
  char* Kb = smem + 8192;
  char* Vb = smem + 16384;
  char* Cb = smem + 24576;

  const uint16_t* WqT = WT;
  const uint16_t* WkT = WT + 65536;
  const uint16_t* WvT = WT + 131072;
  const uint16_t* W0T = WT + 196608;

  const int tid = threadIdx.x;
  const int l = tid & 63;
  const int w = tid >> 6;           // wave 0..15
  const int lane15 = l & 15;
  const int lq = l >> 4;            // lane quad 0..3
  const int rb = w >> 1;            // 16-row block 0..7
  const int ch = w & 1;             // col half
  const int slot0 = blockIdx.x * ROWS;

  // ---- gather: 128 token rows -> bf16 X overlay on smem[0..64K) ----
  #pragma unroll 2
  for (int rl = 0; rl < 8; ++rl) {
    int row = w * 8 + rl;
    int t = s2t[slot0 + row];            // wave-uniform (scalar load)
    uint32_t u0 = 0, u1 = 0;
    if (t >= 0) {
      const float4 v = *reinterpret_cast<const float4*>(emb + (size_t)t * E_ + (l << 2));
      u0 = pk2(bf16rne(v.x), bf16rne(v.y));
      u1 = pk2(bf16rne(v.z), bf16rne(v.w));
    }
    iv2 val; val[0] = (int)u0; val[1] = (int)u1;
    *reinterpret_cast<iv2*>(smem + row * 512 + SWZ(l * 8, row)) = val;
  }
  __syncthreads();

  // ---- X A-fragments: rows rb*16..+16, full K (32 VGPR) ----
  iv4 xf[8];
  const int arow = rb * 16 + lane15;
  #pragma unroll
  for (int ks = 0; ks < 8; ++ks)
    xf[ks] = *reinterpret_cast<const iv4*>(smem + arow * 512 + SWZ(ks * 64 + lq * 16, arow));
  __syncthreads();   // all xf read; low 32K reusable for Q/K/V/C

  fv4 outacc[8];     // 16 rows x 128 cols per wave (AGPR), persists
  #pragma unroll
  for (int i = 0; i < 8; ++i) outacc[i] = fv4{0.f, 0.f, 0.f, 0.f};

  for (int hc = 0; hc < 8; ++hc) {       // 8 chunks of 32 cols (1 head)
    const int c0 = hc * 32;

    // QKV projection: W-fragments read DIRECT from global (L1-resident
    // tile); X from registers. 8 independent b128 loads pipeline with MFMA.
    #define PROJ(Wt, dst)                                                    \
    {                                                                        \
      fv4 a0 = fv4{0.f,0.f,0.f,0.f};                                         \
      const int n0 = ch * 16 + lane15;                                       \
      const char* wb = reinterpret_cast<const char*>(Wt) +                   \
                       (size_t)(c0 + n0) * 512 + lq * 16;                    \
      _Pragma("unroll")                                                      \
      for (int ks = 0; ks < 8; ++ks) {                                       \
        iv4 b0 = *reinterpret_cast<const iv4*>(wb + ks * 64);                \
        mfma32(a0, xf[ks], b0);                                              \
      }                                                                      \
      _Pragma("unroll")                                                      \
      for (int r = 0; r < 4; ++r) {                                          \
        int row = rb * 16 + lq * 4 + r;                                      \
        *reinterpret_cast<uint16_t*>((dst) + LQKV(row, n0 * 2)) =            \
            (uint16_t)bf16rne(a0[r]);                                        \
      }                                                                      \
    }
    PROJ(WqT, Qb);
    PROJ(WkT, Kb);
    PROJ(WvT, Vb);
    __syncthreads();   // Q/K/V visible

    // ---- attention: pair g = rb, head = hc; V-half split by ch ----
    {
      const int frow = rb * 16 + lane15;
      iv4 kf = *reinterpret_cast<const iv4*>(Kb + LQKV(frow, lq * 16));
      iv4 qf = *reinterpret_cast<const iv4*>(Qb + LQKV(frow, lq * 16));
      fv4 s = fv4{0.f, 0.f, 0.f, 0.f};
      mfma32(s, kf, qf);                 // swapped QK^T (pair-dup by ch, cheap)
      float mx = fmaxf(fmaxf(s[0], s[1]), fmaxf(s[2], s[3]));
      mx = fmaxf(mx, __shfl_xor(mx, 16));
      mx = fmaxf(mx, __shfl_xor(mx, 32));
      const float Cc = 0.25503373f;      // log2(e)/sqrt(32)
      float e0 = exp2f((s[0] - mx) * Cc), e1 = exp2f((s[1] - mx) * Cc);
      float e2 = exp2f((s[2] - mx) * Cc), e3 = exp2f((s[3] - mx) * Cc);
      float sum = e0 + e1 + e2 + e3;
      sum += __shfl_xor(sum, 16);
      sum += __shfl_xor(sum, 32);
      float inv = 1.0f / sum;
      iv2 pa; pa[0] = (int)pk2(bf16rne(e0 * inv), bf16rne(e1 * inv));
              pa[1] = (int)pk2(bf16rne(e2 * inv), bf16rne(e3 * inv));
      const int r0 = rb * 16 + lq * 4;
      const int cb = (ch * 16 + lane15) * 2;
      uint32_t v0 = *reinterpret_cast<const uint16_t*>(Vb + LQKV(r0 + 0, cb));
      uint32_t v1 = *reinterpret_cast<const uint16_t*>(Vb + LQKV(r0 + 1, cb));
      uint32_t v2 = *reinterpret_cast<const uint16_t*>(Vb + LQKV(r0 + 2, cb));
      uint32_t v3 = *reinterpret_cast<const uint16_t*>(Vb + LQKV(r0 + 3, cb));
      iv2 bv; bv[0] = (int)pk2(v0, v1); bv[1] = (int)pk2(v2, v3);
      fv4 cacc = fv4{0.f, 0.f, 0.f, 0.f};
      mfma16(cacc, pa, bv);
      #pragma unroll
      for (int r = 0; r < 4; ++r)
        *reinterpret_cast<uint16_t*>(Cb + LQKV(r0 + r, cb)) =
            (uint16_t)bf16rne(cacc[r]);
    }
    __syncthreads();   // Cb visible

    // ---- out += ctx_chunk @ W0[c0:c0+32, :]; W0 direct from global ----
    {
      int ar = rb * 16 + lane15;
      iv4 af = *reinterpret_cast<const iv4*>(Cb + LQKV(ar, lq * 16));
      #pragma unroll
      for (int nt = 0; nt < 8; ++nt) {
        int n = ch * 128 + nt * 16 + lane15;
        iv4 bfg = *reinterpret_cast<const iv4*>(
            reinterpret_cast<const char*>(W0T) + (size_t)n * 512 + c0 * 2 + lq * 16);
        mfma32(outacc[nt], af, bfg);
      }
    }
    __syncthreads();   // Cb/Q/K/V reusable next chunk
    #undef PROJ
  } // hc

  // ---- scatter out (fp32, 64B segments per 16-lane group) ----
  #pragma unroll
  for (int r = 0; r < 4; ++r) {
    int t = s2t[slot0 + rb * 16 + lq * 4 + r];
    if (t < 0) continue;
    #pragma unroll
    for (int nt = 0; nt < 8; ++nt) {
      int col = ch * 128 + nt * 16 + lane15;
      out[(size_t)t * E_ + col] = outacc[nt][r];
    }
  }
}

extern "C" void kernel_launch(void* const* d_in, const int* in_sizes, int n_in,
                              void* d_out, int out_size, void* d_ws, size_t ws_size,
                              hipStream_t stream) {
  (void)in_sizes; (void)n_in; (void)out_size; (void)ws_size;
  const float* emb = (const float*)d_in[0];
  const float* Wq  = (const float*)d_in[1];
  const float* Wk  = (const float*)d_in[2];
  const float* Wv  = (const float*)d_in[3];
  const float* W0  = (const float*)d_in[4];
  const int*   pos = (const int*)d_in[5];
  float* out = (float*)d_out;

  // ws layout: cnt 32KB | s2t 512KB | WT(4x bf16 256x256) 512KB
  int* cnt = (int*)d_ws;
  int* s2t = (int*)((char*)d_ws + 32768);
  uint16_t* WT = (uint16_t*)((char*)d_ws + 32768 + 524288);

  (void)hipFuncSetAttribute(reinterpret_cast<const void*>(k_main),
                            hipFuncAttributeMaxDynamicSharedMemorySize, 65536);

  k_init <<<512, 256, 0, stream>>>(cnt, s2t);
  k_trans<<<dim3(256, 4), 256, 0, stream>>>(Wq, Wk, Wv, W0, WT);
  k_rank <<<512, 256, 0, stream>>>(pos, cnt, s2t);
  k_main <<<NWG, 1024, 65536, stream>>>(emb, s2t, WT, out);
}

// Round 16
// 238.094 us; speedup vs baseline: 2.2940x; 2.2940x over previous
//
#include <hip/hip_runtime.h>
#include <stdint.h>

// Problem constants (fixed instance)
#define B_    32
#define S_    4096
#define E_    256
#define P_    256
#define M_    16
#define G_    (B_*P_)      // 8192 groups
#define NSLOT (G_*M_)      // 131072 slots (== tokens)
#define GPW   8            // groups per workgroup
#define ROWS  128          // 8 groups * 16 slots
#define NWG   (G_/GPW)     // 1024 workgroups

typedef float fv4 __attribute__((ext_vector_type(4)));
typedef int   iv4 __attribute__((ext_vector_type(4)));
typedef int   iv2 __attribute__((ext_vector_type(2)));
typedef __bf16 bv8 __attribute__((ext_vector_type(8)));
typedef short  sv4 __attribute__((ext_vector_type(4)));

__device__ __forceinline__ uint32_t bf16rne(float f) {
  uint32_t u = __builtin_bit_cast(uint32_t, f);
  u += 0x7fffu + ((u >> 16) & 1u);
  return u >> 16;
}
__device__ __forceinline__ uint32_t pk2(uint32_t lo, uint32_t hi) {
  return (lo & 0xffffu) | (hi << 16);
}
// Builtins (NOT inline asm): hazard recognizer must see MFMAs (round-1 NaN).
__device__ __forceinline__ void mfma32(fv4& d, iv4 a, iv4 b) {
  d = __builtin_amdgcn_mfma_f32_16x16x32_bf16(
        __builtin_bit_cast(bv8, a), __builtin_bit_cast(bv8, b), d, 0, 0, 0);
}
__device__ __forceinline__ void mfma16(fv4& d, iv2 a, iv2 b) {
  d = __builtin_amdgcn_mfma_f32_16x16x16bf16_1k(
        __builtin_bit_cast(sv4, a), __builtin_bit_cast(sv4, b), d, 0, 0, 0);
}

// XOR swizzle for 512B rows: flips byte bits 4-6 by row&7 (involution).
#define SWZ(off, row) ((off) ^ (((row) & 7) << 4))
// 64B-row buffers (Q/K/V/C [128][32]bf16) stored [pair][128B], pair-swizzled.
#define LQKV(row, cb) ( ((row) >> 1) * 128 + \
    (((((row) & 1) << 6) + (cb)) ^ ((((row) >> 1) & 7) << 4)) )

// ---------------- prep kernels ----------------
__global__ void k_init(int* cnt, int* s2t) {
  int i = blockIdx.x * 256 + threadIdx.x;
  if (i < G_) cnt[i] = 0;
  if (i < NSLOT) s2t[i] = -1;
}

// WT2: weights pre-arranged in MFMA B-FRAGMENT ORDER so each fragment is one
// contiguous 1KB wave load (lane l at base + l*16 — perfectly coalesced).
// QKV (wsel 0..2): o = ((((hc*2+ch)*8+ks)*64+lane)*8+e)
//   -> element W[k = ks*32+(lane>>4)*8+e][n = hc*32+ch*16+(lane&15)]
// W0  (wsel 3):   o = ((((hc*2+ch)*8+nt)*64+lane)*8+e)
//   -> element W0[k = hc*32+(lane>>4)*8+e][n = ch*128+nt*16+(lane&15)]
// Both are bijections [0,65536) -> (k,n); 128KB per matrix.
__global__ void k_trans(const float* __restrict__ Wq, const float* __restrict__ Wk,
                        const float* __restrict__ Wv, const float* __restrict__ W0,
                        uint16_t* __restrict__ WT2) {
  int o = blockIdx.x * 256 + threadIdx.x;     // 0..65535
  int wsel = blockIdx.y;
  int e    = o & 7;
  int lane = (o >> 3) & 63;
  int s2   = (o >> 9) & 7;                    // ks (QKV) or nt (W0)
  int ch   = (o >> 12) & 1;
  int hc   = (o >> 13) & 7;
  int n, k;
  const float* W;
  if (wsel < 3) {
    W = (wsel == 0) ? Wq : (wsel == 1) ? Wk : Wv;
    n = hc * 32 + ch * 16 + (lane & 15);
    k = s2 * 32 + (lane >> 4) * 8 + e;
  } else {
    W = W0;
    n = ch * 128 + s2 * 16 + (lane & 15);
    k = hc * 32 + (lane >> 4) * 8 + e;
  }
  WT2[(size_t)wsel * 65536 + o] = (uint16_t)bf16rne(W[k * 256 + n]);
}

__global__ void k_rank(const int* __restrict__ pos, int* cnt, int* s2t) {
  int i = blockIdx.x * 256 + threadIdx.x;
  if (i >= B_ * S_) return;
  int p = pos[i];
  if (p < 0 || p >= P_) return;          // invalid -> dropped (stays -1)
  int b = i >> 12;                       // i / S_
  int g = (b << 8) + p;
  int r = atomicAdd(&cnt[g], 1);         // arbitrary slot order: attention is
  if (r < M_) s2t[g * M_ + r] = i;       // permutation-equivariant, so OK
}

// ---------------- fused main kernel ----------------
// 1 WG = 8 groups = 128 rows, 1024 threads = 16 waves (arch VGPR pinned to
// 64 for 1024-thr WGs -> 4 waves/SIMD; measured r2..r14).
// r16 = r15's no-staging structure (proven correct, spill-free, conflict-
// free) with the ONE fix its counters demanded: weight fragments read from
// WT2 in fragment order -> each B-frag = one contiguous 1KB wave load
// (r15's 512B-strided reads cost 16x the transactions -> 575us).
// No vmcnt ledger (compiler waits; immune to spills — r11/12/14 class gone).
// 2 barriers/chunk: {PROJx3; BAR; attn; BAR; W0} — W0 reads only Cb, next
// PROJ writes only Q/K/V (disjoint), attn(hc+1)'s Cb writes are after the
// post-PROJ barrier, so the post-W0 barrier is removable.
__global__ __launch_bounds__(1024) void k_main(
    const float* __restrict__ emb, const int* __restrict__ s2t,
    const uint16_t* __restrict__ WT2, float* __restrict__ out) {
  extern __shared__ char smem[];
  // gather overlay uses [0, 64K); after xf extraction the low 32K is reused:
  char* Qb = smem;              // 8 KiB [128][32] bf16, pair-swizzled
  char* Kb = smem + 8192;
  char* Vb = smem + 16384;
  char* Cb = smem + 24576;

  const int tid = threadIdx.x;
  const int l = tid & 63;
  const int w = tid >> 6;           // wave 0..15
  const int lane15 = l & 15;
  const int lq = l >> 4;            // lane quad 0..3
  const int rb = w >> 1;            // 16-row block 0..7
  const int ch = w & 1;             // col half
  const int slot0 = blockIdx.x * ROWS;

  // ---- gather: 128 token rows -> bf16 X overlay on smem[0..64K) ----
  #pragma unroll 2
  for (int rl = 0; rl < 8; ++rl) {
    int row = w * 8 + rl;
    int t = s2t[slot0 + row];            // wave-uniform (scalar load)
    uint32_t u0 = 0, u1 = 0;
    if (t >= 0) {
      const float4 v = *reinterpret_cast<const float4*>(emb + (size_t)t * E_ + (l << 2));
      u0 = pk2(bf16rne(v.x), bf16rne(v.y));
      u1 = pk2(bf16rne(v.z), bf16rne(v.w));
    }
    iv2 val; val[0] = (int)u0; val[1] = (int)u1;
    *reinterpret_cast<iv2*>(smem + row * 512 + SWZ(l * 8, row)) = val;
  }
  __syncthreads();

  // ---- X A-fragments: rows rb*16..+16, full K (32 VGPR) ----
  iv4 xf[8];
  const int arow = rb * 16 + lane15;
  #pragma unroll
  for (int ks = 0; ks < 8; ++ks)
    xf[ks] = *reinterpret_cast<const iv4*>(smem + arow * 512 + SWZ(ks * 64 + lq * 16, arow));
  __syncthreads();   // all xf read; low 32K reusable for Q/K/V/C

  fv4 outacc[8];     // 16 rows x 128 cols per wave (AGPR), persists
  #pragma unroll
  for (int i = 0; i < 8; ++i) outacc[i] = fv4{0.f, 0.f, 0.f, 0.f};

  const char* WB = reinterpret_cast<const char*>(WT2);

  for (int hc = 0; hc < 8; ++hc) {       // 8 chunks of 32 cols (1 head)
    // per-(hc,ch) fragment bases: wave-uniform + l*16 -> coalesced 1KB loads
    const size_t fb = (size_t)hc * 16384 + (size_t)ch * 8192 + (size_t)l * 16;

    // QKV projection: B-frags direct from WT2 (one 1KB coalesced load each)
    #define PROJ(wsel, dst)                                                  \
    {                                                                        \
      fv4 a0 = fv4{0.f,0.f,0.f,0.f};                                         \
      const char* wb = WB + (size_t)(wsel) * 131072 + fb;                    \
      const int n0 = ch * 16 + lane15;                                       \
      _Pragma("unroll")                                                      \
      for (int ks = 0; ks < 8; ++ks) {                                       \
        iv4 b0 = *reinterpret_cast<const iv4*>(wb + ks * 1024);              \
        mfma32(a0, xf[ks], b0);                                              \
      }                                                                      \
      _Pragma("unroll")                                                      \
      for (int r = 0; r < 4; ++r) {                                          \
        int row = rb * 16 + lq * 4 + r;                                      \
        *reinterpret_cast<uint16_t*>((dst) + LQKV(row, n0 * 2)) =            \
            (uint16_t)bf16rne(a0[r]);                                        \
      }                                                                      \
    }
    PROJ(0, Qb);
    PROJ(1, Kb);
    PROJ(2, Vb);
    __syncthreads();   // Q/K/V visible

    // ---- attention: pair g = rb, head = hc; V-half split by ch ----
    {
      const int frow = rb * 16 + lane15;
      iv4 kf = *reinterpret_cast<const iv4*>(Kb + LQKV(frow, lq * 16));
      iv4 qf = *reinterpret_cast<const iv4*>(Qb + LQKV(frow, lq * 16));
      fv4 s = fv4{0.f, 0.f, 0.f, 0.f};
      mfma32(s, kf, qf);                 // swapped QK^T (pair-dup by ch, cheap)
      float mx = fmaxf(fmaxf(s[0], s[1]), fmaxf(s[2], s[3]));
      mx = fmaxf(mx, __shfl_xor(mx, 16));
      mx = fmaxf(mx, __shfl_xor(mx, 32));
      const float Cc = 0.25503373f;      // log2(e)/sqrt(32)
      float e0 = exp2f((s[0] - mx) * Cc), e1 = exp2f((s[1] - mx) * Cc);
      float e2 = exp2f((s[2] - mx) * Cc), e3 = exp2f((s[3] - mx) * Cc);
      float sum = e0 + e1 + e2 + e3;
      sum += __shfl_xor(sum, 16);
      sum += __shfl_xor(sum, 32);
      float inv = 1.0f / sum;
      iv2 pa; pa[0] = (int)pk2(bf16rne(e0 * inv), bf16rne(e1 * inv));
              pa[1] = (int)pk2(bf16rne(e2 * inv), bf16rne(e3 * inv));
      const int r0 = rb * 16 + lq * 4;
      const int cb = (ch * 16 + lane15) * 2;
      uint32_t v0 = *reinterpret_cast<const uint16_t*>(Vb + LQKV(r0 + 0, cb));
      uint32_t v1 = *reinterpret_cast<const uint16_t*>(Vb + LQKV(r0 + 1, cb));
      uint32_t v2 = *reinterpret_cast<const uint16_t*>(Vb + LQKV(r0 + 2, cb));
      uint32_t v3 = *reinterpret_cast<const uint16_t*>(Vb + LQKV(r0 + 3, cb));
      iv2 bv; bv[0] = (int)pk2(v0, v1); bv[1] = (int)pk2(v2, v3);
      fv4 cacc = fv4{0.f, 0.f, 0.f, 0.f};
      mfma16(cacc, pa, bv);
      #pragma unroll
      for (int r = 0; r < 4; ++r)
        *reinterpret_cast<uint16_t*>(Cb + LQKV(r0 + r, cb)) =
            (uint16_t)bf16rne(cacc[r]);
    }
    __syncthreads();   // Cb visible

    // ---- out += ctx_chunk @ W0[c0:c0+32, :]; W0 frags direct from WT2 ----
    {
      int ar = rb * 16 + lane15;
      iv4 af = *reinterpret_cast<const iv4*>(Cb + LQKV(ar, lq * 16));
      const char* w0b = WB + (size_t)3 * 131072 + fb;
      #pragma unroll
      for (int nt = 0; nt < 8; ++nt) {
        iv4 bfg = *reinterpret_cast<const iv4*>(w0b + nt * 1024);
        mfma32(outacc[nt], af, bfg);
      }
    }
    // no barrier: W0 read only Cb; next PROJ writes only Q/K/V (disjoint);
    // attn(hc+1)'s Cb writes happen after the next post-PROJ barrier.
    #undef PROJ
  } // hc

  // ---- scatter out (fp32, 64B segments per 16-lane group) ----
  #pragma unroll
  for (int r = 0; r < 4; ++r) {
    int t = s2t[slot0 + rb * 16 + lq * 4 + r];
    if (t < 0) continue;
    #pragma unroll
    for (int nt = 0; nt < 8; ++nt) {
      int col = ch * 128 + nt * 16 + lane15;
      out[(size_t)t * E_ + col] = outacc[nt][r];
    }
  }
}

extern "C" void kernel_launch(void* const* d_in, const int* in_sizes, int n_in,
                              void* d_out, int out_size, void* d_ws, size_t ws_size,
                              hipStream_t stream) {
  (void)in_sizes; (void)n_in; (void)out_size; (void)ws_size;
  const float* emb = (const float*)d_in[0];
  const float* Wq  = (const float*)d_in[1];
  const float* Wk  = (const float*)d_in[2];
  const float* Wv  = (const float*)d_in[3];
  const float* W0  = (const float*)d_in[4];
  const int*   pos = (const int*)d_in[5];
  float* out = (float*)d_out;

  // ws layout: cnt 32KB | s2t 512KB | WT2(4x bf16 frag-order) 512KB
  int* cnt = (int*)d_ws;
  int* s2t = (int*)((char*)d_ws + 32768);
  uint16_t* WT2 = (uint16_t*)((char*)d_ws + 32768 + 524288);

  (void)hipFuncSetAttribute(reinterpret_cast<const void*>(k_main),
                            hipFuncAttributeMaxDynamicSharedMemorySize, 65536);

  k_init <<<512, 256, 0, stream>>>(cnt, s2t);
  k_trans<<<dim3(256, 4), 256, 0, stream>>>(Wq, Wk, Wv, W0, WT2);
  k_rank <<<512, 256, 0, stream>>>(pos, cnt, s2t);
  k_main <<<NWG, 1024, 65536, stream>>>(emb, s2t, WT2, out);
}